// Round 8
// baseline (1664.906 us; speedup 1.0000x reference)
//
#include <hip/hip_runtime.h>
#include <math.h>

#define KD    1024   // k
#define BATCH 2048
#define XD    784
#define YD    10

typedef _Float16 f16;
typedef _Float16 f16x8 __attribute__((ext_vector_type(8)));
typedef _Float16 f16x4 __attribute__((ext_vector_type(4)));
typedef float    f32x4 __attribute__((ext_vector_type(4)));

// ---------------------------------------------------------------------------
// async global->LDS, 16B per lane: per-lane global src, wave-uniform LDS dest;
// lane l lands at dst + 16*l.
// ---------------------------------------------------------------------------
__device__ __forceinline__ void gll16(const void* g, void* l)
{
    __builtin_amdgcn_global_load_lds(
        (const __attribute__((address_space(1))) void*)g,
        (__attribute__((address_space(3))) void*)l,
        16, 0, 0);
}

// ---------------------------------------------------------------------------
// C[i][j] = sum_d A[d][i] * B[d][j]   (A: [K x M], B: [K x N], both k-major)
// fp32 setup GEMM (WtW = Wx^T Wx, XtW = x^T Wx).
// ---------------------------------------------------------------------------
#define TS  64
#define KS  32
#define LDP 68

__global__ __launch_bounds__(256) void atb_kernel(const float* __restrict__ A,
                                                  const float* __restrict__ B,
                                                  float* __restrict__ C,
                                                  int M, int N, int K)
{
    __shared__ float As[KS][LDP];
    __shared__ float Bs[KS][LDP];
    const int tid = threadIdx.x;
    const int tx = tid & 15, ty = tid >> 4;
    const int i0 = blockIdx.y * TS, j0 = blockIdx.x * TS;
    float acc[4][4] = {};

    for (int k0 = 0; k0 < K; k0 += KS) {
#pragma unroll
        for (int q = 0; q < 2; ++q) {
            const int f  = tid + q * 256;
            const int kr = f >> 4;
            const int cc = (f & 15) << 2;
            float4 av = make_float4(0.f, 0.f, 0.f, 0.f);
            float4 bv = av;
            if (k0 + kr < K) {
                av = *(const float4*)(A + (size_t)(k0 + kr) * M + i0 + cc);
                bv = *(const float4*)(B + (size_t)(k0 + kr) * N + j0 + cc);
            }
            *(float4*)&As[kr][cc] = av;
            *(float4*)&Bs[kr][cc] = bv;
        }
        __syncthreads();
#pragma unroll
        for (int kk = 0; kk < KS; ++kk) {
            const float4 a4 = *(const float4*)&As[kk][ty << 2];
            const float4 b4 = *(const float4*)&Bs[kk][tx << 2];
            const float a[4] = {a4.x, a4.y, a4.z, a4.w};
            const float b[4] = {b4.x, b4.y, b4.z, b4.w};
#pragma unroll
            for (int r = 0; r < 4; ++r)
#pragma unroll
                for (int c = 0; c < 4; ++c)
                    acc[r][c] = fmaf(a[r], b[c], acc[r][c]);
        }
        __syncthreads();
    }
#pragma unroll
    for (int r = 0; r < 4; ++r) {
        float4 o = make_float4(acc[r][0], acc[r][1], acc[r][2], acc[r][3]);
        *(float4*)(C + (size_t)(i0 + (ty << 2) + r) * N + j0 + (tx << 2)) = o;
    }
}

// ---------------------------------------------------------------------------
// fp32 -> f16 hi/lo split (scaled). Used for B = 256*WtW.
// ---------------------------------------------------------------------------
__global__ __launch_bounds__(256) void split_kernel(const float* __restrict__ src,
                                                    f16* __restrict__ hi,
                                                    f16* __restrict__ lo,
                                                    float scale, int n4)
{
    const int i = blockIdx.x * 256 + threadIdx.x;
    if (i >= n4) return;
    const float4 v = ((const float4*)src)[i];
    const float a0 = v.x * scale, a1 = v.y * scale, a2 = v.z * scale, a3 = v.w * scale;
    const f16 h0 = (f16)a0, h1 = (f16)a1, h2 = (f16)a2, h3 = (f16)a3;
    const f16 l0 = (f16)(a0 - (float)h0);
    const f16 l1 = (f16)(a1 - (float)h1);
    const f16 l2 = (f16)(a2 - (float)h2);
    const f16 l3 = (f16)(a3 - (float)h3);
    f16x4 hv = {h0, h1, h2, h3};
    f16x4 lv = {l0, l1, l2, l3};
    ((f16x4*)hi)[i] = hv;
    ((f16x4*)lo)[i] = lv;
}

// fp32 -> f16 (round), vectorized x8
__global__ __launch_bounds__(256) void tof16_kernel(const float* __restrict__ src,
                                                    f16* __restrict__ dst, int n8)
{
    const int i = blockIdx.x * 256 + threadIdx.x;
    if (i >= n8) return;
    const f32x4 a = ((const f32x4*)src)[2 * i];
    const f32x4 b = ((const f32x4*)src)[2 * i + 1];
    f16x8 o;
#pragma unroll
    for (int j = 0; j < 4; ++j) { o[j] = (f16)a[j]; o[j + 4] = (f16)b[j]; }
    ((f16x8*)dst)[i] = o;
}

// ---------------------------------------------------------------------------
// Fused FISTA step, 2-pass split-f16 MFMA, 8-wave / 2-waves-per-SIMD:
//   acc = Y @ (256*WtW)  via  Yh*Bh + Yh*Bl   (fp32 accumulate)
//   grad = acc/256 - XtW ; Hout = max(Y - grad*invL, 0); Yout = Hout + cm*(Hout-Hin)
// BM=128, BN=64, BK=64; 512 thr = 8 waves (4m x 2n, wave-tile 32x32);
// grid 16x16 = 256 blocks = 1 block/CU -> 2 waves/SIMD (intra-block overlap).
// LDS: 2 buffers x 32 KiB, fragment-chunk-major (every wave ds op = contiguous
// 1 KiB, conflict-free). Stage kt+1 into other buffer via global_load_lds w16
// at top of kt; vmcnt(0)+barrier at boundary (loads had a full kt to land).
// XCD swizzle: per-XCD region = 4 m-panels x 8 n-panels (~4MB, fits L2).
// MFMA per-element accumulation order identical to rounds 3-7 -> bit-identical.
// ---------------------------------------------------------------------------
#define BMF 128
#define BNF 64

__global__ __launch_bounds__(512, 2) void fista8(
    const f16* __restrict__ yhP,   // A operand + epilogue y  [BATCH][KD]
    const f16* __restrict__ hhP,   // epilogue h              [BATCH][KD]
    const f16* __restrict__ bhiP,  // 256*WtW hi plane        [KD][KD]
    const f16* __restrict__ bloP,  // 256*WtW lo plane
    const float* __restrict__ xtw, // fp32 [BATCH][KD]
    const float* __restrict__ invLp, float cm,
    f16* __restrict__ HO, f16* __restrict__ YO)
{
    __shared__ char lds[65536];    // 2 bufs x 32 KiB; epilogue reuses

    const int t    = threadIdx.x;
    const int lane = t & 63;
    const int wid  = t >> 6;       // 0..7
    const int wm   = wid >> 1;     // 0..3 (32-row block)
    const int wn   = wid & 1;      // 0..1 (32-col block)

    // XCD swizzle: x = XCD, j = local index; region 4m x 8n per XCD (~4MB < L2)
    const int bid = blockIdx.y * gridDim.x + blockIdx.x;   // 0..255
    const int xc  = bid & 7, j = bid >> 3;                 // j: 0..31
    const int m0  = ((xc >> 1) * 4 + (j >> 3)) * BMF;      // 16 m-tiles
    const int n0  = ((xc & 1) * 8 + (j & 7)) * BNF;        // 16 n-tiles

    // --- staging: 32 chunks of 1 KiB per k-tile (A: c=0..15, B: c=16..31);
    // each wave stages 4 chunks c = wid*4+i.
    // A chunk c: row-group g=c&7, k-step s=c>>3; lane l -> row 16g+(l&15),
    //            k 32s+8(l>>4).
    // B chunk cb=c-16: col-group g=cb&3, plane p=(cb>>2)&1, k-step s=cb>>3
    //            (cols via WtW symmetry -> k-contiguous).
    const f16* gsrc[4];
    int ldst[4];
#pragma unroll
    for (int i = 0; i < 4; ++i) {
        const int c = wid * 4 + i;
        if (c < 16) {
            const int g = c & 7, s = c >> 3;
            gsrc[i] = yhP + (size_t)(m0 + 16 * g + (lane & 15)) * KD
                          + 32 * s + 8 * (lane >> 4);
        } else {
            const int cb = c - 16;
            const int g = cb & 3, p = (cb >> 2) & 1, s = cb >> 3;
            const f16* pl = p ? bloP : bhiP;
            gsrc[i] = pl + (size_t)(n0 + 16 * g + (lane & 15)) * KD
                         + 32 * s + 8 * (lane >> 4);
        }
        ldst[i] = c * 1024;
    }

    auto stage = [&](int buf, int kt) {
        char* base = lds + buf * 32768;
#pragma unroll
        for (int i = 0; i < 4; ++i)
            gll16(gsrc[i] + kt * 64, base + ldst[i]);
    };

    f32x4 acc[2][2] = {};

    // prologue: stage k-tile 0 into buf 0
    stage(0, 0);
    asm volatile("s_waitcnt vmcnt(0)" ::: "memory");
    __builtin_amdgcn_s_barrier();
    asm volatile("" ::: "memory");

#pragma unroll
    for (int kt = 0; kt < 16; ++kt) {
        const int buf = kt & 1;
        if (kt < 15) stage(buf ^ 1, kt + 1);
        const char* bb = lds + buf * 32768;

        f16x8 Af[2][2], Bf[2][2][2];
#pragma unroll
        for (int s = 0; s < 2; ++s) {
#pragma unroll
            for (int f = 0; f < 2; ++f)
                Af[s][f] = *(const f16x8*)(bb + ((s << 3) + wm * 2 + f) * 1024 + lane * 16);
#pragma unroll
            for (int p = 0; p < 2; ++p)
#pragma unroll
                for (int b = 0; b < 2; ++b)
                    Bf[s][p][b] = *(const f16x8*)(bb + 16384 + ((s << 3) + (p << 2) + wn * 2 + b) * 1024 + lane * 16);
        }
#pragma unroll
        for (int s = 0; s < 2; ++s) {
#pragma unroll
            for (int f = 0; f < 2; ++f)
#pragma unroll
                for (int b = 0; b < 2; ++b)
                    acc[f][b] = __builtin_amdgcn_mfma_f32_16x16x32_f16(Af[s][f], Bf[s][0][b], acc[f][b], 0, 0, 0);
#pragma unroll
            for (int f = 0; f < 2; ++f)
#pragma unroll
                for (int b = 0; b < 2; ++b)
                    acc[f][b] = __builtin_amdgcn_mfma_f32_16x16x32_f16(Af[s][f], Bf[s][1][b], acc[f][b], 0, 0, 0);
        }

        // boundary: next buffer fully staged (loads had the whole kt to land)
        if (kt < 15) { asm volatile("s_waitcnt vmcnt(0)" ::: "memory"); }
        __builtin_amdgcn_s_barrier();
        asm volatile("" ::: "memory");
    }

    // ---- epilogue: acc -> LDS fp32 [128][68] -> linear global I/O ----
    float* eb = (float*)lds;
#pragma unroll
    for (int f = 0; f < 2; ++f)
#pragma unroll
        for (int b = 0; b < 2; ++b) {
            const int r0 = wm * 32 + 16 * f + 4 * (lane >> 4);
            const int cl = wn * 32 + 16 * b + (lane & 15);
#pragma unroll
            for (int r = 0; r < 4; ++r)
                eb[(r0 + r) * 68 + cl] = acc[f][b][r];
        }
    __syncthreads();

    const int row = t >> 2;            // 0..127
    const int cb  = (t & 3) * 16;
    const float invL  = invLp[0];
    const float invLs = invL * 0.00390625f;   // invL/256 (fold WtW scale)
    const size_t gb = (size_t)(m0 + row) * KD + n0 + cb;
#pragma unroll
    for (int q = 0; q < 2; ++q) {
        const f32x4 a0 = *(const f32x4*)(eb + row * 68 + cb + q * 8);
        const f32x4 a1 = *(const f32x4*)(eb + row * 68 + cb + q * 8 + 4);
        const size_t g8 = gb + q * 8;
        const f16x8 yh8 = *(const f16x8*)(yhP + g8);
        const f16x8 hh8 = *(const f16x8*)(hhP + g8);
        const f32x4 xt0 = *(const f32x4*)(xtw + g8);
        const f32x4 xt1 = *(const f32x4*)(xtw + g8 + 4);
        f16x8 oh, oy;
#pragma unroll
        for (int jj = 0; jj < 8; ++jj) {
            const float av = (jj < 4) ? a0[jj] : a1[jj - 4];
            const float xv = (jj < 4) ? xt0[jj] : xt1[jj - 4];
            const float yv = (float)yh8[jj];
            const float hv = (float)hh8[jj];
            const float t1 = fmaf(invL, xv, yv);
            const float hn = fmaxf(fmaf(-invLs, av, t1), 0.f);
            const float yn = fmaf(cm, hn - hv, hn);
            oh[jj] = (f16)hn;
            oy[jj] = (f16)yn;
        }
        *(f16x8*)(HO + g8) = oh;
        *(f16x8*)(YO + g8) = oy;
    }
}

// ---------------------------------------------------------------------------
// Power iteration (deterministic, no atomics): wout = WtW @ (win/||win||)
// ---------------------------------------------------------------------------
__global__ void initw_kernel(float* __restrict__ w)
{
    w[threadIdx.x] = 0.03125f;               // 1/sqrt(1024), ||w||=1 exactly
}

__global__ __launch_bounds__(256) void matvec_n_kernel(const float* __restrict__ WtW,
                                                       const float* __restrict__ win,
                                                       float* __restrict__ wout)
{
    __shared__ float red[4];
    __shared__ float invnS;
    const int t = threadIdx.x;
    const int wave = t >> 6, lane = t & 63;

    const float4 wv = *(const float4*)(win + t * 4);
    float ss = wv.x * wv.x + wv.y * wv.y + wv.z * wv.z + wv.w * wv.w;
#pragma unroll
    for (int off = 32; off > 0; off >>= 1) ss += __shfl_down(ss, off);
    if (lane == 0) red[wave] = ss;
    __syncthreads();
    if (t == 0) invnS = 1.0f / (sqrtf(red[0] + red[1] + red[2] + red[3]) + 1e-12f);
    __syncthreads();
    const float invn = invnS;

    const int row = blockIdx.x * 4 + wave;
    const float* rp = WtW + (size_t)row * KD;
    float s = 0.f;
#pragma unroll
    for (int q = 0; q < KD / 64; ++q)
        s = fmaf(rp[lane + 64 * q], win[lane + 64 * q] * invn, s);
#pragma unroll
    for (int off = 32; off > 0; off >>= 1) s += __shfl_down(s, off);
    if (lane == 0) wout[row] = s;
}

__global__ __launch_bounds__(1024) void rayleigh_n_kernel(const float* __restrict__ wprev,
                                                          const float* __restrict__ wlast,
                                                          float* __restrict__ invL)
{
    __shared__ float red[16];
    __shared__ float invnS;
    const int t = threadIdx.x;
    const float a = wprev[t];
    float ss = a * a;
#pragma unroll
    for (int off = 32; off > 0; off >>= 1) ss += __shfl_down(ss, off);
    if ((t & 63) == 0) red[t >> 6] = ss;
    __syncthreads();
    if (t < 64) {
        float v = (t < 16) ? red[t] : 0.f;
#pragma unroll
        for (int off = 8; off > 0; off >>= 1) v += __shfl_down(v, off);
        if (t == 0) invnS = 1.0f / (sqrtf(v) + 1e-12f);
    }
    __syncthreads();
    float s = (a * invnS) * wlast[t];
#pragma unroll
    for (int off = 32; off > 0; off >>= 1) s += __shfl_down(s, off);
    __syncthreads();
    if ((t & 63) == 0) red[t >> 6] = s;
    __syncthreads();
    if (t == 0) {
        float tot = 0.f;
#pragma unroll
        for (int i = 0; i < 16; ++i) tot += red[i];
        invL[0] = 1.0f / tot;
    }
}

// ---------------------------------------------------------------------------
// out[i][b] = sum_j Wy[i][j] * H[b][j]   (out: [YD x BATCH])
// ---------------------------------------------------------------------------
__global__ __launch_bounds__(256) void ypred_kernel(const float* __restrict__ Wy,
                                                    const f16* __restrict__ hh,
                                                    float* __restrict__ out)
{
    const int wave = threadIdx.x >> 6;
    const int lane = threadIdx.x & 63;
    const int b    = blockIdx.x * 4 + wave;
    float p[YD] = {};
    const f16* hp = hh + (size_t)b * KD;
#pragma unroll 4
    for (int q = 0; q < KD / 64; ++q) {
        const int j = lane + 64 * q;
        const float hv = (float)hp[j];
#pragma unroll
        for (int i = 0; i < YD; ++i)
            p[i] = fmaf(Wy[i * KD + j], hv, p[i]);
    }
#pragma unroll
    for (int i = 0; i < YD; ++i) {
        float s = p[i];
#pragma unroll
        for (int off = 32; off > 0; off >>= 1)
            s += __shfl_down(s, off);
        if (lane == 0) out[(size_t)i * BATCH + b] = s;
    }
}

// ---------------------------------------------------------------------------
extern "C" void kernel_launch(void* const* d_in, const int* in_sizes, int n_in,
                              void* d_out, int out_size, void* d_ws, size_t ws_size,
                              hipStream_t stream)
{
    const float* x      = (const float*)d_in[0];   // [784 x 2048]
    const float* Wx     = (const float*)d_in[1];   // [784 x 1024]
    const float* Wy     = (const float*)d_in[2];   // [10 x 1024]
    const float* h_init = (const float*)d_in[3];   // [2048 x 1024]
    float* out = (float*)d_out;                    // [10 x 2048]

    char* base = (char*)d_ws;
    const size_t MB = 1 << 20;
    float* WtW  = (float*)(base + 0 * MB);         // 4 MB
    float* XtW  = (float*)(base + 4 * MB);         // 8 MB
    f16* bhiP   = (f16*)(base + 12 * MB);          // 2 MB
    f16* bloP   = (f16*)(base + 14 * MB);          // 2 MB
    f16* h0f    = (f16*)(base + 16 * MB);          // 4 MB
    f16* hA     = (f16*)(base + 20 * MB);
    f16* yA     = (f16*)(base + 24 * MB);
    f16* hB     = (f16*)(base + 28 * MB);
    f16* yB     = (f16*)(base + 32 * MB);
    float* wA   = (float*)(base + 36 * MB);
    float* wB   = (float*)(base + 36 * MB + 8192);
    float* invL = (float*)(base + 36 * MB + 16384);

    // 1) WtW = Wx^T Wx ; XtW = x^T Wx
    atb_kernel<<<dim3(KD / TS, KD / TS), 256, 0, stream>>>(Wx, Wx, WtW, KD, KD, XD);
    atb_kernel<<<dim3(KD / TS, BATCH / TS), 256, 0, stream>>>(x, Wx, XtW, BATCH, KD, XD);

    // 2) split 256*WtW into f16 hi/lo planes; h_init -> f16
    split_kernel<<<(KD * KD / 4 + 255) / 256, 256, 0, stream>>>(WtW, bhiP, bloP, 256.0f, KD * KD / 4);
    tof16_kernel<<<(BATCH * KD / 8 + 255) / 256, 256, 0, stream>>>(h_init, h0f, BATCH * KD / 8);

    // 3) Lipschitz via power iteration (spectrum ~rank-1 dominant; 11 matvecs
    //    reach fp32 convergence). writes: it even -> wB, odd -> wA;
    //    it=9 -> wA(u10), it=10 -> wB(u11).
    initw_kernel<<<1, 1024, 0, stream>>>(wA);
    float* wcur = wA; float* wnxt = wB;
    for (int it = 0; it < 11; ++it) {
        matvec_n_kernel<<<KD / 4, 256, 0, stream>>>(WtW, wcur, wnxt);
        float* tmp = wcur; wcur = wnxt; wnxt = tmp;
    }
    rayleigh_n_kernel<<<1, 1024, 0, stream>>>(wA, wB, invL);  // (u10, u11)

    // 4) 60 FISTA iterations (t restarts at iter 50: y = h, t = 1)
    float t = 1.0f;
    const f16 *yin = h0f, *hin = h0f;
    int outSel = 1;                                 // 1 -> A set, 0 -> B set
    for (int n = 0; n < 60; ++n) {
        if (n == 50) { t = 1.0f; yin = hin; }
        const float tn = 0.5f * (1.0f + sqrtf(1.0f + 4.0f * t * t));
        const float cm = (t - 1.0f) / tn;
        f16* ho = outSel ? hA : hB;
        f16* yo = outSel ? yA : yB;
        fista8<<<dim3(KD / BNF, BATCH / BMF), 512, 0, stream>>>(
            yin, hin, bhiP, bloP, XtW, invL, cm, ho, yo);
        t = tn;
        hin = ho; yin = yo;
        outSel ^= 1;
    }

    // 5) out = Wy @ h^T
    ypred_kernel<<<BATCH / 4, 256, 0, stream>>>(Wy, hin, out);
}

// Round 9
// 1340.743 us; speedup vs baseline: 1.2418x; 1.2418x over previous
//
#include <hip/hip_runtime.h>
#include <math.h>

#define KD    1024   // k
#define BATCH 2048
#define XD    784
#define YD    10

typedef _Float16 f16;
typedef _Float16 f16x8 __attribute__((ext_vector_type(8)));
typedef _Float16 f16x4 __attribute__((ext_vector_type(4)));
typedef float    f32x4 __attribute__((ext_vector_type(4)));

// ---------------------------------------------------------------------------
// async global->LDS, 16B per lane: per-lane global src, wave-uniform LDS dest;
// lane l lands at dst + 16*l.
// ---------------------------------------------------------------------------
__device__ __forceinline__ void gll16(const void* g, void* l)
{
    __builtin_amdgcn_global_load_lds(
        (const __attribute__((address_space(1))) void*)g,
        (__attribute__((address_space(3))) void*)l,
        16, 0, 0);
}

#define TS  64
#define KS  32
#define LDP 68

// ---------------------------------------------------------------------------
// atb tile body: C[i][j] = sum_d A[d][i]*B[d][j]  (A:[K x M], B:[K x N])
// ---------------------------------------------------------------------------
__device__ __forceinline__ void atb_body(const float* __restrict__ A,
                                         const float* __restrict__ B,
                                         float* __restrict__ C,
                                         int M, int N, int K, int bx, int by,
                                         float (*As)[LDP], float (*Bs)[LDP])
{
    const int tid = threadIdx.x;
    const int tx = tid & 15, ty = tid >> 4;
    const int i0 = by * TS, j0 = bx * TS;
    float acc[4][4] = {};

    for (int k0 = 0; k0 < K; k0 += KS) {
#pragma unroll
        for (int q = 0; q < 2; ++q) {
            const int f  = tid + q * 256;
            const int kr = f >> 4;
            const int cc = (f & 15) << 2;
            float4 av = make_float4(0.f, 0.f, 0.f, 0.f);
            float4 bv = av;
            if (k0 + kr < K) {
                av = *(const float4*)(A + (size_t)(k0 + kr) * M + i0 + cc);
                bv = *(const float4*)(B + (size_t)(k0 + kr) * N + j0 + cc);
            }
            *(float4*)&As[kr][cc] = av;
            *(float4*)&Bs[kr][cc] = bv;
        }
        __syncthreads();
#pragma unroll
        for (int kk = 0; kk < KS; ++kk) {
            const float4 a4 = *(const float4*)&As[kk][ty << 2];
            const float4 b4 = *(const float4*)&Bs[kk][tx << 2];
            const float a[4] = {a4.x, a4.y, a4.z, a4.w};
            const float b[4] = {b4.x, b4.y, b4.z, b4.w};
#pragma unroll
            for (int r = 0; r < 4; ++r)
#pragma unroll
                for (int c = 0; c < 4; ++c)
                    acc[r][c] = fmaf(a[r], b[c], acc[r][c]);
        }
        __syncthreads();
    }
#pragma unroll
    for (int r = 0; r < 4; ++r) {
        float4 o = make_float4(acc[r][0], acc[r][1], acc[r][2], acc[r][3]);
        *(float4*)(C + (size_t)(i0 + (ty << 2) + r) * N + j0 + (tx << 2)) = o;
    }
}

// ---------------------------------------------------------------------------
// Fused setup (one launch): blocks [0,256) WtW = Wx^T Wx; [256,768) XtW = x^T Wx;
// [768,1792) h_init -> f16; block 1792: power-iteration init vector.
// The two independent atb jobs (19% occupancy each) now overlap.
// ---------------------------------------------------------------------------
__global__ __launch_bounds__(256) void setup_fused(const float* __restrict__ x,
                                                   const float* __restrict__ Wx,
                                                   const float* __restrict__ h_init,
                                                   float* __restrict__ WtW,
                                                   float* __restrict__ XtW,
                                                   f16* __restrict__ h0f,
                                                   float* __restrict__ w0)
{
    __shared__ float As[KS][LDP];
    __shared__ float Bs[KS][LDP];
    const int blk = blockIdx.x;
    if (blk < 256) {
        atb_body(Wx, Wx, WtW, KD, KD, XD, blk & 15, blk >> 4, As, Bs);
    } else if (blk < 768) {
        const int l = blk - 256;
        atb_body(x, Wx, XtW, BATCH, KD, XD, l & 15, l >> 4, As, Bs);
    } else if (blk < 1792) {
        const int i = (blk - 768) * 256 + threadIdx.x;     // x8 groups, 262144 total
        const f32x4 a = ((const f32x4*)h_init)[2 * i];
        const f32x4 b = ((const f32x4*)h_init)[2 * i + 1];
        f16x8 o;
#pragma unroll
        for (int j = 0; j < 4; ++j) { o[j] = (f16)a[j]; o[j + 4] = (f16)b[j]; }
        ((f16x8*)h0f)[i] = o;
    } else {
        ((float4*)w0)[threadIdx.x] = make_float4(0.03125f, 0.03125f, 0.03125f, 0.03125f);
    }
}

// ---------------------------------------------------------------------------
// Fused convert (one launch): blocks [0,512): bhi = f16(256*WtW);
// blocks [512,2560): XtW -> f16 hi/lo planes (epilogue operand compression).
// ---------------------------------------------------------------------------
__global__ __launch_bounds__(256) void convert_fused(const float* __restrict__ WtW,
                                                     const float* __restrict__ XtW,
                                                     f16* __restrict__ bhi,
                                                     f16* __restrict__ xth,
                                                     f16* __restrict__ xtl)
{
    const int blk = blockIdx.x;
    if (blk < 512) {
        const int i = blk * 256 + threadIdx.x;             // x8, 131072 total
        const f32x4 a = ((const f32x4*)WtW)[2 * i];
        const f32x4 b = ((const f32x4*)WtW)[2 * i + 1];
        f16x8 o;
#pragma unroll
        for (int j = 0; j < 4; ++j) {
            o[j]     = (f16)(256.0f * a[j]);
            o[j + 4] = (f16)(256.0f * b[j]);
        }
        ((f16x8*)bhi)[i] = o;
    } else {
        const int i = (blk - 512) * 256 + threadIdx.x;     // x4, 524288 total
        const float4 v = ((const float4*)XtW)[i];
        const f16 h0 = (f16)v.x, h1 = (f16)v.y, h2 = (f16)v.z, h3 = (f16)v.w;
        f16x4 hv = {h0, h1, h2, h3};
        f16x4 lv = {(f16)(v.x - (float)h0), (f16)(v.y - (float)h1),
                    (f16)(v.z - (float)h2), (f16)(v.w - (float)h3)};
        ((f16x4*)xth)[i] = hv;
        ((f16x4*)xtl)[i] = lv;
    }
}

// ---------------------------------------------------------------------------
// Fused FISTA step, SINGLE-pass f16 MFMA (traffic-minimized):
//   acc = Y @ f16(256*WtW) ; grad = acc/256 - XtW(f16 hi+lo)
//   Hout = max(Y - grad*invL, 0); Yout = Hout + cm*(Hout - Hin)
// BM=128, BN=64, BK=64; 512 thr = 8 waves (4m x 2n, wave-tile 32x32);
// grid 16x16 = 256 blocks = 1 block/CU, 2 waves/SIMD. LDS: 2 bufs x 24 KiB
// fragment-chunk-major (conflict-free). Stage kt+1 via global_load_lds w16;
// vmcnt(0)+barrier at boundary. XCD swizzle: 4m x 8n panels per XCD (<L2).
// ---------------------------------------------------------------------------
#define BMF 128
#define BNF 64

__global__ __launch_bounds__(512, 2) void fista9(
    const f16* __restrict__ yhP,   // A operand + epilogue y  [BATCH][KD]
    const f16* __restrict__ hhP,   // epilogue h              [BATCH][KD]
    const f16* __restrict__ bhiP,  // f16(256*WtW)            [KD][KD]
    const f16* __restrict__ xthP,  // XtW hi plane (f16)      [BATCH][KD]
    const f16* __restrict__ xtlP,  // XtW lo plane (f16)
    const float* __restrict__ invLp, float cm,
    f16* __restrict__ HO, f16* __restrict__ YO)
{
    __shared__ char lds[49152];    // 2 bufs x 24 KiB; epilogue reuses

    const int t    = threadIdx.x;
    const int lane = t & 63;
    const int wid  = t >> 6;       // 0..7
    const int wm   = wid >> 1;     // 0..3 (32-row block)
    const int wn   = wid & 1;      // 0..1 (32-col block)

    // XCD swizzle: region 4m x 8n per XCD (~3MB working set < 4MB L2)
    const int bid = blockIdx.y * gridDim.x + blockIdx.x;   // 0..255
    const int xc  = bid & 7, j = bid >> 3;                 // j: 0..31
    const int m0  = ((xc >> 1) * 4 + (j >> 3)) * BMF;      // 16 m-tiles
    const int n0  = ((xc & 1) * 8 + (j & 7)) * BNF;        // 16 n-tiles

    // staging: 24 chunks of 1 KiB per k-tile (A: c=0..15, B: c=16..23);
    // each wave stages 3 chunks c = wid*3+i.
    // A chunk c: row-group g=c&7, k-step s=c>>3; lane l -> row 16g+(l&15),
    //            k 32s+8(l>>4).
    // B chunk cb=c-16: col-group g=cb&3, k-step s=cb>>2 (cols via WtW symmetry).
    const f16* gsrc[3];
    int ldst[3];
#pragma unroll
    for (int i = 0; i < 3; ++i) {
        const int c = wid * 3 + i;
        if (c < 16) {
            const int g = c & 7, s = c >> 3;
            gsrc[i] = yhP + (size_t)(m0 + 16 * g + (lane & 15)) * KD
                          + 32 * s + 8 * (lane >> 4);
        } else {
            const int cb = c - 16;
            const int g = cb & 3, s = cb >> 2;
            gsrc[i] = bhiP + (size_t)(n0 + 16 * g + (lane & 15)) * KD
                           + 32 * s + 8 * (lane >> 4);
        }
        ldst[i] = c * 1024;
    }

    auto stage = [&](int buf, int kt) {
        char* base = lds + buf * 24576;
#pragma unroll
        for (int i = 0; i < 3; ++i)
            gll16(gsrc[i] + kt * 64, base + ldst[i]);
    };

    f32x4 acc[2][2] = {};

    // prologue: stage k-tile 0 into buf 0
    stage(0, 0);
    asm volatile("s_waitcnt vmcnt(0)" ::: "memory");
    __builtin_amdgcn_s_barrier();
    asm volatile("" ::: "memory");

#pragma unroll
    for (int kt = 0; kt < 16; ++kt) {
        const int buf = kt & 1;
        if (kt < 15) stage(buf ^ 1, kt + 1);
        const char* bb = lds + buf * 24576;

        f16x8 Af[2][2], Bf[2][2];
#pragma unroll
        for (int s = 0; s < 2; ++s) {
#pragma unroll
            for (int f = 0; f < 2; ++f)
                Af[s][f] = *(const f16x8*)(bb + ((s << 3) + wm * 2 + f) * 1024 + lane * 16);
#pragma unroll
            for (int b = 0; b < 2; ++b)
                Bf[s][b] = *(const f16x8*)(bb + 16384 + ((s << 2) + wn * 2 + b) * 1024 + lane * 16);
        }
#pragma unroll
        for (int s = 0; s < 2; ++s)
#pragma unroll
            for (int f = 0; f < 2; ++f)
#pragma unroll
                for (int b = 0; b < 2; ++b)
                    acc[f][b] = __builtin_amdgcn_mfma_f32_16x16x32_f16(Af[s][f], Bf[s][b], acc[f][b], 0, 0, 0);

        // boundary: next buffer fully staged (loads had the whole kt to land)
        if (kt < 15) { asm volatile("s_waitcnt vmcnt(0)" ::: "memory"); }
        __builtin_amdgcn_s_barrier();
        asm volatile("" ::: "memory");
    }

    // ---- epilogue: acc -> LDS fp32 [128][68] -> linear global I/O ----
    float* eb = (float*)lds;
#pragma unroll
    for (int f = 0; f < 2; ++f)
#pragma unroll
        for (int b = 0; b < 2; ++b) {
            const int r0 = wm * 32 + 16 * f + 4 * (lane >> 4);
            const int cl = wn * 32 + 16 * b + (lane & 15);
#pragma unroll
            for (int r = 0; r < 4; ++r)
                eb[(r0 + r) * 68 + cl] = acc[f][b][r];
        }
    __syncthreads();

    const int row = t >> 2;            // 0..127
    const int cb  = (t & 3) * 16;
    const float invL  = invLp[0];
    const float invLs = invL * 0.00390625f;   // invL/256 (fold WtW scale)
    const size_t gb = (size_t)(m0 + row) * KD + n0 + cb;
#pragma unroll
    for (int q = 0; q < 2; ++q) {
        const f32x4 a0 = *(const f32x4*)(eb + row * 68 + cb + q * 8);
        const f32x4 a1 = *(const f32x4*)(eb + row * 68 + cb + q * 8 + 4);
        const size_t g8 = gb + q * 8;
        const f16x8 yh8 = *(const f16x8*)(yhP + g8);
        const f16x8 hh8 = *(const f16x8*)(hhP + g8);
        const f16x8 xh8 = *(const f16x8*)(xthP + g8);
        const f16x8 xl8 = *(const f16x8*)(xtlP + g8);
        f16x8 oh, oy;
#pragma unroll
        for (int jj = 0; jj < 8; ++jj) {
            const float av = (jj < 4) ? a0[jj] : a1[jj - 4];
            const float xv = (float)xh8[jj] + (float)xl8[jj];
            const float yv = (float)yh8[jj];
            const float hv = (float)hh8[jj];
            const float t1 = fmaf(invL, xv, yv);
            const float hn = fmaxf(fmaf(-invLs, av, t1), 0.f);
            const float yn = fmaf(cm, hn - hv, hn);
            oh[jj] = (f16)hn;
            oy[jj] = (f16)yn;
        }
        *(f16x8*)(HO + g8) = oh;
        *(f16x8*)(YO + g8) = oy;
    }
}

// ---------------------------------------------------------------------------
// Power iteration (deterministic, no atomics): wout = WtW @ (win/||win||)
// ---------------------------------------------------------------------------
__global__ __launch_bounds__(256) void matvec_n_kernel(const float* __restrict__ WtW,
                                                       const float* __restrict__ win,
                                                       float* __restrict__ wout)
{
    __shared__ float red[4];
    __shared__ float invnS;
    const int t = threadIdx.x;
    const int wave = t >> 6, lane = t & 63;

    const float4 wv = *(const float4*)(win + t * 4);
    float ss = wv.x * wv.x + wv.y * wv.y + wv.z * wv.z + wv.w * wv.w;
#pragma unroll
    for (int off = 32; off > 0; off >>= 1) ss += __shfl_down(ss, off);
    if (lane == 0) red[wave] = ss;
    __syncthreads();
    if (t == 0) invnS = 1.0f / (sqrtf(red[0] + red[1] + red[2] + red[3]) + 1e-12f);
    __syncthreads();
    const float invn = invnS;

    const int row = blockIdx.x * 4 + wave;
    const float* rp = WtW + (size_t)row * KD;
    float s = 0.f;
#pragma unroll
    for (int q = 0; q < KD / 64; ++q)
        s = fmaf(rp[lane + 64 * q], win[lane + 64 * q] * invn, s);
#pragma unroll
    for (int off = 32; off > 0; off >>= 1) s += __shfl_down(s, off);
    if (lane == 0) wout[row] = s;
}

__global__ __launch_bounds__(1024) void rayleigh_n_kernel(const float* __restrict__ wprev,
                                                          const float* __restrict__ wlast,
                                                          float* __restrict__ invL)
{
    __shared__ float red[16];
    __shared__ float invnS;
    const int t = threadIdx.x;
    const float a = wprev[t];
    float ss = a * a;
#pragma unroll
    for (int off = 32; off > 0; off >>= 1) ss += __shfl_down(ss, off);
    if ((t & 63) == 0) red[t >> 6] = ss;
    __syncthreads();
    if (t < 64) {
        float v = (t < 16) ? red[t] : 0.f;
#pragma unroll
        for (int off = 8; off > 0; off >>= 1) v += __shfl_down(v, off);
        if (t == 0) invnS = 1.0f / (sqrtf(v) + 1e-12f);
    }
    __syncthreads();
    float s = (a * invnS) * wlast[t];
#pragma unroll
    for (int off = 32; off > 0; off >>= 1) s += __shfl_down(s, off);
    __syncthreads();
    if ((t & 63) == 0) red[t >> 6] = s;
    __syncthreads();
    if (t == 0) {
        float tot = 0.f;
#pragma unroll
        for (int i = 0; i < 16; ++i) tot += red[i];
        invL[0] = 1.0f / tot;
    }
}

// ---------------------------------------------------------------------------
// out[i][b] = sum_j Wy[i][j] * H[b][j]   (out: [YD x BATCH])
// ---------------------------------------------------------------------------
__global__ __launch_bounds__(256) void ypred_kernel(const float* __restrict__ Wy,
                                                    const f16* __restrict__ hh,
                                                    float* __restrict__ out)
{
    const int wave = threadIdx.x >> 6;
    const int lane = threadIdx.x & 63;
    const int b    = blockIdx.x * 4 + wave;
    float p[YD] = {};
    const f16* hp = hh + (size_t)b * KD;
#pragma unroll 4
    for (int q = 0; q < KD / 64; ++q) {
        const int j = lane + 64 * q;
        const float hv = (float)hp[j];
#pragma unroll
        for (int i = 0; i < YD; ++i)
            p[i] = fmaf(Wy[i * KD + j], hv, p[i]);
    }
#pragma unroll
    for (int i = 0; i < YD; ++i) {
        float s = p[i];
#pragma unroll
        for (int off = 32; off > 0; off >>= 1)
            s += __shfl_down(s, off);
        if (lane == 0) out[(size_t)i * BATCH + b] = s;
    }
}

// ---------------------------------------------------------------------------
extern "C" void kernel_launch(void* const* d_in, const int* in_sizes, int n_in,
                              void* d_out, int out_size, void* d_ws, size_t ws_size,
                              hipStream_t stream)
{
    const float* x      = (const float*)d_in[0];   // [784 x 2048]
    const float* Wx     = (const float*)d_in[1];   // [784 x 1024]
    const float* Wy     = (const float*)d_in[2];   // [10 x 1024]
    const float* h_init = (const float*)d_in[3];   // [2048 x 1024]
    float* out = (float*)d_out;                    // [10 x 2048]

    char* base = (char*)d_ws;
    const size_t MB = 1 << 20;
    float* WtW  = (float*)(base + 0 * MB);         // 4 MB
    float* XtW  = (float*)(base + 4 * MB);         // 8 MB
    f16* bhiP   = (f16*)(base + 12 * MB);          // 2 MB
    f16* xthP   = (f16*)(base + 14 * MB);          // 4 MB
    f16* xtlP   = (f16*)(base + 18 * MB);          // 4 MB
    f16* h0f    = (f16*)(base + 22 * MB);          // 4 MB
    f16* hA     = (f16*)(base + 26 * MB);
    f16* yA     = (f16*)(base + 30 * MB);
    f16* hB     = (f16*)(base + 34 * MB);
    f16* yB     = (f16*)(base + 38 * MB);
    float* wA   = (float*)(base + 42 * MB);
    float* wB   = (float*)(base + 42 * MB + 8192);
    float* invL = (float*)(base + 42 * MB + 16384);

    // 1) fused setup: WtW, XtW, h_init->f16, power-init   (one launch)
    setup_fused<<<1793, 256, 0, stream>>>(x, Wx, h_init, WtW, XtW, h0f, wA);

    // 2) fused convert: bhi = f16(256*WtW); XtW -> f16 hi/lo
    convert_fused<<<2560, 256, 0, stream>>>(WtW, XtW, bhiP, xthP, xtlP);

    // 3) Lipschitz via power iteration (spectrum ~rank-1 dominant; 11 matvecs
    //    reach fp32 convergence). writes: it even -> wB, odd -> wA;
    //    it=9 -> wA(u10), it=10 -> wB(u11).
    float* wcur = wA; float* wnxt = wB;
    for (int it = 0; it < 11; ++it) {
        matvec_n_kernel<<<KD / 4, 256, 0, stream>>>(WtW, wcur, wnxt);
        float* tmp = wcur; wcur = wnxt; wnxt = tmp;
    }
    rayleigh_n_kernel<<<1, 1024, 0, stream>>>(wA, wB, invL);  // (u10, u11)

    // 4) 60 FISTA iterations (t restarts at iter 50: y = h, t = 1)
    float t = 1.0f;
    const f16 *yin = h0f, *hin = h0f;
    int outSel = 1;                                 // 1 -> A set, 0 -> B set
    for (int n = 0; n < 60; ++n) {
        if (n == 50) { t = 1.0f; yin = hin; }
        const float tn = 0.5f * (1.0f + sqrtf(1.0f + 4.0f * t * t));
        const float cm = (t - 1.0f) / tn;
        f16* ho = outSel ? hA : hB;
        f16* yo = outSel ? yA : yB;
        fista9<<<dim3(KD / BNF, BATCH / BMF), 512, 0, stream>>>(
            yin, hin, bhiP, xthP, xtlP, invL, cm, ho, yo);
        t = tn;
        hin = ho; yin = yo;
        outSel ^= 1;
    }

    // 5) out = Wy @ h^T
    ypred_kernel<<<BATCH / 4, 256, 0, stream>>>(Wy, hin, out);
}